// Round 19
// baseline (229.962 us; speedup 1.0000x reference)
//
#include <hip/hip_runtime.h>
#include <math.h>

typedef __attribute__((ext_vector_type(8)))  _Float16 f16x8;
typedef __attribute__((ext_vector_type(4)))  _Float16 f16x4;
typedef __attribute__((ext_vector_type(2)))  __fp16   h16x2;   // cvt_pkrtz/fdot2 type
typedef __attribute__((ext_vector_type(4)))  float    f32x4;
typedef __attribute__((ext_vector_type(16))) float    f32x16;
typedef unsigned int u32;

static constexpr int B  = 4;
static constexpr int S  = 2048;
static constexpr int D  = 1024;
static constexpr int H  = 16;
static constexpr int HD = 64;

// C = 0.125 * log2(e) : folded into Q at projection time.
#define CSCALE 0.18033688011112042f
#define MSHIFT -5.770780163555854f

union U64cvt { f16x4 h; ushort4 u; };
union W4 { u32 w[4]; f16x8 v; };

__device__ __forceinline__ void gld16(const void* g, void* l) {
    __builtin_amdgcn_global_load_lds((const u32*)g, (u32*)l, 16, 0, 0);
}

__device__ __forceinline__ void cvtwr16(const float4& x, const float4& y, void* dst) {
    W4 w;
    w.w[0] = __builtin_bit_cast(u32, __builtin_amdgcn_cvt_pkrtz(x.x, x.y));
    w.w[1] = __builtin_bit_cast(u32, __builtin_amdgcn_cvt_pkrtz(x.z, x.w));
    w.w[2] = __builtin_bit_cast(u32, __builtin_amdgcn_cvt_pkrtz(y.x, y.y));
    w.w[3] = __builtin_bit_cast(u32, __builtin_amdgcn_cvt_pkrtz(y.z, y.w));
    *(f16x8*)dst = w.v;
}

// ---------------------------------------------------------------------------
// Prepass: convert q,k,v + wq,wk,wv fp32 -> f16 row-major (memory-bound).
// ---------------------------------------------------------------------------
__global__ __launch_bounds__(256)
void cvt_prep(const float* __restrict__ q, const float* __restrict__ k,
              const float* __restrict__ v,
              const float* __restrict__ wq, const float* __restrict__ wk,
              const float* __restrict__ wv,
              unsigned short* __restrict__ dst)
{
    const int c = blockIdx.x * 256 + threadIdx.x;   // chunk id (8 elems)
    const float* src;
    size_t idx;
    if (c < 3145728) {
        const int a = c >> 20;
        src = (a == 0) ? q : (a == 1) ? k : v;
        idx = (size_t)(c & 1048575) * 8;
    } else {
        const int c2 = c - 3145728;
        const int a = c2 >> 17;
        src = (a == 0) ? wq : (a == 1) ? wk : wv;
        idx = (size_t)(c2 & 131071) * 8;
    }
    const float4 x = *(const float4*)(src + idx);
    const float4 y = *(const float4*)(src + idx + 4);
    cvtwr16(x, y, dst + (size_t)c * 8);
}

// ---------------------------------------------------------------------------
// Mask-fragment prepass: per (b, tile, kb) a 64-lane f16x8 A-fragment whose
// elem0 = fmaf(1-mask[kv], -30000, MSHIFT) (kv = t*64+kb*32+(lane&31)),
// rest 0. Used as a rank-1 MFMA term to add mask+shift to QK^T scores.
// Layout: mf[b*32768 + t*1024 + kb*512 + lane*8 + j].
// ---------------------------------------------------------------------------
__global__ __launch_bounds__(256)
void mf_prep(const float* __restrict__ mask, unsigned short* __restrict__ mf)
{
    const int cm   = blockIdx.x * 256 + threadIdx.x;   // 0..16383
    const int b    = cm >> 12;
    const int rem  = cm & 4095;
    const int t    = rem >> 7;
    const int kb   = (rem >> 6) & 1;
    const int lane = rem & 63;
    const int kv   = t * 64 + kb * 32 + (lane & 31);
    const float m  = fmaf(1.0f - mask[(size_t)b * S + kv], -30000.0f, MSHIFT);
    W4 w;
    w.w[0] = __builtin_bit_cast(u32, __builtin_amdgcn_cvt_pkrtz(m, 0.0f));
    w.w[1] = 0; w.w[2] = 0; w.w[3] = 0;
    *(f16x8*)(mf + (size_t)cm * 8) = w.v;
}

// ---------------------------------------------------------------------------
// f16 QKV projection, m97 structure: pure global_load_lds staging, double-
// buffered, one barrier per k-step, pre-swizzled source addresses.
//   z=0: Q head layout, PRE-SCALED by CSCALE; z=1: K FRAGMENT-MAJOR;
//   z=2: V FRAGMENT-MAJOR.
// ---------------------------------------------------------------------------
__global__ __launch_bounds__(256)
void proj_f16(const unsigned short* __restrict__ af16,
              const unsigned short* __restrict__ wf16,
              const float* __restrict__ bqp, const float* __restrict__ bkp,
              const float* __restrict__ bvp,
              unsigned short* __restrict__ outs)
{
    const int bid = blockIdx.x;
    const int xcd = bid & 7;
    const int idx = bid >> 3;
    const int z   = idx / 64;
    const int r2  = idx - z * 64;
    const int mpl = r2 >> 3;
    const int np  = r2 & 7;
    const int mp  = (xcd >> 1) * 16 + (xcd & 1) * 8 + mpl;
    const int m0  = mp * 128;
    const int n0  = np * 128;

    const unsigned short* A  = af16 + (size_t)z * 8388608;
    const unsigned short* Wf = wf16 + (size_t)z * 1048576;
    const float* bias = (z == 0) ? bqp : (z == 1) ? bkp : bvp;
    unsigned short* out = outs + (size_t)z * 8388608;

    const int tid  = threadIdx.x;
    const int lane = tid & 63;
    const int wid  = tid >> 6;
    const int wr   = wid >> 1;
    const int wc   = wid & 1;

    __shared__ __align__(16) unsigned char lA[2][8192];
    __shared__ __align__(16) unsigned char lB[2][8192];

    f32x4 acc[4][4];
#pragma unroll
    for (int i = 0; i < 4; ++i)
#pragma unroll
        for (int j = 0; j < 4; ++j) acc[i][j] = (f32x4){0.f, 0.f, 0.f, 0.f};

    int grow[2], gcol[2], lbase[2];
#pragma unroll
    for (int i = 0; i < 2; ++i) {
        const int c = tid + 256 * i;
        grow[i]  = c >> 2;
        gcol[i]  = ((c & 3) - (grow[i] >> 1)) & 3;
        lbase[i] = (c & ~63) * 16;
    }

#pragma unroll
    for (int i = 0; i < 2; ++i) {
        gld16(A  + (size_t)(m0 + grow[i]) * D + gcol[i] * 8, lA[0] + lbase[i]);
        gld16(Wf + (size_t)(n0 + grow[i]) * D + gcol[i] * 8, lB[0] + lbase[i]);
    }
    __syncthreads();

    for (int kt = 0; kt < 32; ++kt) {
        const int cb = kt & 1, nx = cb ^ 1;

        if (kt < 31) {
            const int k1 = (kt + 1) * 32;
#pragma unroll
            for (int i = 0; i < 2; ++i) {
                gld16(A  + (size_t)(m0 + grow[i]) * D + k1 + gcol[i] * 8, lA[nx] + lbase[i]);
                gld16(Wf + (size_t)(n0 + grow[i]) * D + k1 + gcol[i] * 8, lB[nx] + lbase[i]);
            }
        }

        f16x8 af[4], bf[4];
#pragma unroll
        for (int mi = 0; mi < 4; ++mi) {
            const int row = wr * 64 + mi * 16 + (lane & 15);
            const int cc  = ((lane >> 4) + (row >> 1)) & 3;
            af[mi] = *(const f16x8*)(lA[cb] + row * 64 + cc * 16);
        }
#pragma unroll
        for (int ni = 0; ni < 4; ++ni) {
            const int row = wc * 64 + ni * 16 + (lane & 15);
            const int cc  = ((lane >> 4) + (row >> 1)) & 3;
            bf[ni] = *(const f16x8*)(lB[cb] + row * 64 + cc * 16);
        }

        __builtin_amdgcn_s_setprio(1);
#pragma unroll
        for (int mi = 0; mi < 4; ++mi)
#pragma unroll
            for (int ni = 0; ni < 4; ++ni)
                acc[mi][ni] = __builtin_amdgcn_mfma_f32_16x16x32_f16(af[mi], bf[ni], acc[mi][ni], 0, 0, 0);
        __builtin_amdgcn_s_setprio(0);

        __syncthreads();
    }

#pragma unroll
    for (int mi = 0; mi < 4; ++mi) {
        const int gmBase = m0 + wr * 64 + mi * 16 + ((lane >> 4) << 2);
        const int b  = gmBase >> 11;
        const int s0 = gmBase & 2047;
        const int tV   = s0 >> 6;
        const int kv6  = s0 & 63;
        const int ksg  = kv6 >> 4;
        const int hi2v = (kv6 >> 3) & 1;
        const int jb   = kv6 & 7;
#pragma unroll
        for (int ni = 0; ni < 4; ++ni) {
            const int gn = n0 + wc * 64 + ni * 16 + (lane & 15);
            const float bb = bias[gn];
            const int hh = gn >> 6;
            const int hd = gn & 63;
            const size_t bhbase = ((size_t)b * H + hh) * ((size_t)S * HD);
            if (z == 0) {
#pragma unroll
                for (int r = 0; r < 4; ++r) {
                    const int gm = gmBase + r;
                    const _Float16 hv = (_Float16)((acc[mi][ni][r] + bb) * CSCALE);
                    out[bhbase + (size_t)(gm & 2047) * HD + hd] =
                        __builtin_bit_cast(unsigned short, hv);
                }
            } else if (z == 1) {
                const int ks   = hd >> 4;
                const int hi2k = (hd >> 3) & 1;
                const int j    = hd & 7;
#pragma unroll
                for (int r = 0; r < 4; ++r) {
                    const int s = (gmBase + r) & 2047;
                    const int t = s >> 6;
                    const int q = ((s >> 5) & 1) * 4 + ks;
                    const _Float16 hv = (_Float16)(acc[mi][ni][r] + bb);
                    out[bhbase + (((size_t)t * 8 + q) * 64 + hi2k * 32 + (s & 31)) * 8 + j] =
                        __builtin_bit_cast(unsigned short, hv);
                }
            } else {
                const int nb  = hd >> 5;
                const int c31 = hd & 31;
                const int q   = nb * 4 + ksg;
                U64cvt uu;
#pragma unroll
                for (int r = 0; r < 4; ++r)
                    uu.h[r] = (_Float16)(acc[mi][ni][r] + bb);
                *(ushort4*)(out + bhbase +
                    (((size_t)tV * 8 + q) * 64 + hi2v * 32 + c31) * 8 + jb) = uu.u;
            }
        }
    }
}

// ---------------------------------------------------------------------------
// FALLBACK projection (fp32 reg-staging) if ws is too small. Same layouts,
// z=0 pre-scaled by CSCALE.
// ---------------------------------------------------------------------------
__global__ __launch_bounds__(256)
void proj_qkv(const float* __restrict__ qi, const float* __restrict__ ki,
              const float* __restrict__ vi,
              const float* __restrict__ wqp, const float* __restrict__ wkp,
              const float* __restrict__ wvp,
              const float* __restrict__ bqp, const float* __restrict__ bkp,
              const float* __restrict__ bvp,
              unsigned short* __restrict__ ws)
{
    const int bid = blockIdx.x;
    const int xcd = bid & 7;
    const int idx = bid >> 3;
    const int z   = idx / 64;
    const int r2  = idx - z * 64;
    const int mpl = r2 >> 3;
    const int np  = r2 & 7;
    const int mp  = (xcd >> 1) * 16 + (xcd & 1) * 8 + mpl;
    const int m0  = mp * 128;
    const int n0  = np * 128;

    const float* A    = (z == 0) ? qi  : (z == 1) ? ki  : vi;
    const float* W    = (z == 0) ? wqp : (z == 1) ? wkp : wvp;
    const float* bias = (z == 0) ? bqp : (z == 1) ? bkp : bvp;
    unsigned short* out = ws + (size_t)z * ((size_t)B * S * D);

    const int tid  = threadIdx.x;
    const int lane = tid & 63;
    const int wid  = tid >> 6;
    const int wr   = wid >> 1;
    const int wc   = wid & 1;

    __shared__ __align__(16) unsigned char lA[2][8192];
    __shared__ __align__(16) unsigned char lB[2][8192];

    f32x4 acc[4][4];
#pragma unroll
    for (int i = 0; i < 4; ++i)
#pragma unroll
        for (int j = 0; j < 4; ++j) acc[i][j] = (f32x4){0.f, 0.f, 0.f, 0.f};

    const int rb = (lane >> 4) * 16;

    int srow[2], sc8[2], soff[2];
#pragma unroll
    for (int i = 0; i < 2; ++i) {
        const int f = tid + 256 * i;
        srow[i] = f >> 2;
        sc8[i]  = f & 3;
        soff[i] = ((f >> 2) * 64 + (f & 3) * 16) ^ ((((f >> 2)) & 7) << 4);
    }

#pragma unroll
    for (int i = 0; i < 2; ++i) {
        const float* pa = A + (size_t)(m0 + srow[i]) * D + sc8[i] * 8;
        const float* pw = W + (size_t)(n0 + srow[i]) * D + sc8[i] * 8;
        cvtwr16(*(const float4*)pa, *(const float4*)(pa + 4), lA[0] + soff[i]);
        cvtwr16(*(const float4*)pw, *(const float4*)(pw + 4), lB[0] + soff[i]);
    }
    float4 pa0[2], pa1[2], pw0[2], pw1[2];
#pragma unroll
    for (int i = 0; i < 2; ++i) {
        const float* pa = A + (size_t)(m0 + srow[i]) * D + 32 + sc8[i] * 8;
        const float* pw = W + (size_t)(n0 + srow[i]) * D + 32 + sc8[i] * 8;
        pa0[i] = *(const float4*)pa;  pa1[i] = *(const float4*)(pa + 4);
        pw0[i] = *(const float4*)pw;  pw1[i] = *(const float4*)(pw + 4);
    }
    __syncthreads();

    for (int kt = 0; kt < 32; ++kt) {
        const int cb = kt & 1, nx = cb ^ 1;
        if (kt < 31) {
#pragma unroll
            for (int i = 0; i < 2; ++i) {
                cvtwr16(pa0[i], pa1[i], lA[nx] + soff[i]);
                cvtwr16(pw0[i], pw1[i], lB[nx] + soff[i]);
            }
        }
        f16x8 af[4], bf[4];
#pragma unroll
        for (int mi = 0; mi < 4; ++mi) {
            const int row = wr * 64 + mi * 16 + (lane & 15);
            af[mi] = *(const f16x8*)(lA[cb] + ((row * 64 + rb) ^ ((row & 7) << 4)));
        }
#pragma unroll
        for (int ni = 0; ni < 4; ++ni) {
            const int row = wc * 64 + ni * 16 + (lane & 15);
            bf[ni] = *(const f16x8*)(lB[cb] + ((row * 64 + rb) ^ ((row & 7) << 4)));
        }
        if (kt < 30) {
            const int k2 = (kt + 2) * 32;
#pragma unroll
            for (int i = 0; i < 2; ++i) {
                const float* pa = A + (size_t)(m0 + srow[i]) * D + k2 + sc8[i] * 8;
                const float* pw = W + (size_t)(n0 + srow[i]) * D + k2 + sc8[i] * 8;
                pa0[i] = *(const float4*)pa;  pa1[i] = *(const float4*)(pa + 4);
                pw0[i] = *(const float4*)pw;  pw1[i] = *(const float4*)(pw + 4);
            }
        }
        __builtin_amdgcn_s_setprio(1);
#pragma unroll
        for (int mi = 0; mi < 4; ++mi)
#pragma unroll
            for (int ni = 0; ni < 4; ++ni)
                acc[mi][ni] = __builtin_amdgcn_mfma_f32_16x16x32_f16(af[mi], bf[ni], acc[mi][ni], 0, 0, 0);
        __builtin_amdgcn_s_setprio(0);
        __syncthreads();
    }

#pragma unroll
    for (int mi = 0; mi < 4; ++mi) {
        const int gmBase = m0 + wr * 64 + mi * 16 + ((lane >> 4) << 2);
        const int b  = gmBase >> 11;
        const int s0 = gmBase & 2047;
        const int tV   = s0 >> 6;
        const int kv6  = s0 & 63;
        const int ksg  = kv6 >> 4;
        const int hi2v = (kv6 >> 3) & 1;
        const int jb   = kv6 & 7;
#pragma unroll
        for (int ni = 0; ni < 4; ++ni) {
            const int gn = n0 + wc * 64 + ni * 16 + (lane & 15);
            const float bb = bias[gn];
            const int hh = gn >> 6;
            const int hd = gn & 63;
            const size_t bhbase = ((size_t)b * H + hh) * ((size_t)S * HD);
            if (z == 0) {
#pragma unroll
                for (int r = 0; r < 4; ++r) {
                    const int gm = gmBase + r;
                    const _Float16 hv = (_Float16)((acc[mi][ni][r] + bb) * CSCALE);
                    out[bhbase + (size_t)(gm & 2047) * HD + hd] =
                        __builtin_bit_cast(unsigned short, hv);
                }
            } else if (z == 1) {
                const int ks   = hd >> 4;
                const int hi2k = (hd >> 3) & 1;
                const int j    = hd & 7;
#pragma unroll
                for (int r = 0; r < 4; ++r) {
                    const int s = (gmBase + r) & 2047;
                    const int t = s >> 6;
                    const int q = ((s >> 5) & 1) * 4 + ks;
                    const _Float16 hv = (_Float16)(acc[mi][ni][r] + bb);
                    out[bhbase + (((size_t)t * 8 + q) * 64 + hi2k * 32 + (s & 31)) * 8 + j] =
                        __builtin_bit_cast(unsigned short, hv);
                }
            } else {
                const int nb  = hd >> 5;
                const int c31 = hd & 31;
                const int q   = nb * 4 + ksg;
                U64cvt uu;
#pragma unroll
                for (int r = 0; r < 4; ++r)
                    uu.h[r] = (_Float16)(acc[mi][ni][r] + bb);
                *(ushort4*)(out + bhbase +
                    (((size_t)tV * 8 + q) * 64 + hi2v * 32 + c31) * 8 + jb) = uu.u;
            }
        }
    }
}

// ---------------------------------------------------------------------------
// Flash attention fwd: r18 structure + MFMA-folded mask/scale softmax.
// Q pre-scaled by CSCALE; mask+shift added via one rank-1 MFMA per kb
// (A = mask fragment, B = ones fragment). Softmax = pure exp2 per element.
// First MFMA per kb uses a loop-invariant zero C (no per-tile zero-init).
// ---------------------------------------------------------------------------
__global__ __launch_bounds__(256)
void attn_f16(const unsigned short* __restrict__ qh,
              const unsigned short* __restrict__ kf,
              const unsigned short* __restrict__ vf,
              const unsigned short* __restrict__ mf,
              float* __restrict__ out)
{
    const int flat = blockIdx.y * gridDim.x + blockIdx.x;   // 0..1023
    const int sw   = (flat & 7) * 128 + (flat >> 3);
    const int bh   = sw >> 4;
    const int q0   = (sw & 15) * 128;

    const int b = bh >> 4;
    const int h = bh & 15;
    const unsigned short* Q  = qh + (size_t)bh * S * HD;
    const unsigned short* KF = kf + (size_t)bh * S * HD;   // frag-major
    const unsigned short* VF = vf + (size_t)bh * S * HD;   // frag-major
    const unsigned short* MFb = mf + (size_t)b * 32768;

    const int tid  = threadIdx.x;
    const int lane = tid & 63;
    const int wid  = tid >> 6;
    const int l31  = lane & 31;
    const int hi2  = lane >> 5;

    __shared__ __align__(16) unsigned char Kl[2][8192];
    __shared__ __align__(16) unsigned char Vl[2][8192];

    const int ldsA = wid * 1024;
    const int ldsB = wid * 1024 + 4096;
    const int g0   = tid * 8;
    const int g1   = tid * 8 + 2048;

    // hoist Q (pre-scaled) as the B-operand
    f16x8 aq[4];
    {
        const unsigned short* qrow = Q + (size_t)(q0 + wid * 32 + l31) * HD;
#pragma unroll
        for (int ks = 0; ks < 4; ++ks)
            aq[ks] = *(const f16x8*)(qrow + ks * 16 + hi2 * 8);
    }

    // ones B-fragment: 1 at k=0 (hi2==0, j==0), else 0
    f16x8 aqone = {};
    if (hi2 == 0) aqone[0] = (_Float16)1.0f;

    f32x16 fzero = {};

    float ls0 = 0.f, ls1 = 0.f;
    f32x16 accO[2];
    accO[0] = (f32x16){};
    accO[1] = (f32x16){};
    const h16x2 one2 = {(__fp16)1.0f, (__fp16)1.0f};

    // ---- prologue: stage tile 0; load tile-0 mask frags ----
    gld16(KF + g0, Kl[0] + ldsA);
    gld16(KF + g1, Kl[0] + ldsB);
    gld16(VF + g0, Vl[0] + ldsA);
    gld16(VF + g1, Vl[0] + ldsB);
    f16x8 mfc0 = *(const f16x8*)(MFb + lane * 8);
    f16x8 mfc1 = *(const f16x8*)(MFb + 512 + lane * 8);
    __syncthreads();

    const int lane16 = lane * 16;
    for (int t = 0; t < S / 64; ++t) {
        const int cb = t & 1, nx = cb ^ 1;
        const unsigned char* Kc = Kl[cb];
        const unsigned char* Vc = Vl[cb];

        // ---- stage next tile FIRST + prefetch next mask frags ----
        f16x8 mfn0, mfn1;
        if (t < S / 64 - 1) {
            const int nt = (t + 1) * 4096;
            gld16(KF + nt + g0, Kl[nx] + ldsA);
            gld16(KF + nt + g1, Kl[nx] + ldsB);
            gld16(VF + nt + g0, Vl[nx] + ldsA);
            gld16(VF + nt + g1, Vl[nx] + ldsB);
            mfn0 = *(const f16x8*)(MFb + (t + 1) * 1024 + lane * 8);
            mfn1 = *(const f16x8*)(MFb + (t + 1) * 1024 + 512 + lane * 8);
        }

        // ---- QK^T (swapped) + rank-1 mask add ----
        f32x16 p[2];
        __builtin_amdgcn_s_setprio(1);
#pragma unroll
        for (int kb = 0; kb < 2; ++kb) {
            {
                const f16x8 ak = *(const f16x8*)(Kc + lane16 + (kb * 4 + 0) * 1024);
                p[kb] = __builtin_amdgcn_mfma_f32_32x32x16_f16(ak, aq[0], fzero, 0, 0, 0);
            }
#pragma unroll
            for (int ks = 1; ks < 4; ++ks) {
                const f16x8 ak = *(const f16x8*)(Kc + lane16 + (kb * 4 + ks) * 1024);
                p[kb] = __builtin_amdgcn_mfma_f32_32x32x16_f16(ak, aq[ks], p[kb], 0, 0, 0);
            }
            p[kb] = __builtin_amdgcn_mfma_f32_32x32x16_f16(kb == 0 ? mfc0 : mfc1, aqone, p[kb], 0, 0, 0);
        }
        __builtin_amdgcn_s_setprio(0);

        // ---- pure-exp2 softmax + in-register P->A-frag ----
        f16x8 pa[4];
#pragma unroll
        for (int kb = 0; kb < 2; ++kb) {
            float pe[16];
#pragma unroll
            for (int e = 0; e < 16; ++e)
                pe[e] = exp2f(p[kb][e]);
#pragma unroll
            for (int ks2 = 0; ks2 < 2; ++ks2) {
                const int o = ks2 * 8;
                const h16x2 h0 = __builtin_amdgcn_cvt_pkrtz(pe[o + 0], pe[o + 1]);
                const h16x2 h1 = __builtin_amdgcn_cvt_pkrtz(pe[o + 2], pe[o + 3]);
                const h16x2 h2 = __builtin_amdgcn_cvt_pkrtz(pe[o + 4], pe[o + 5]);
                const h16x2 h3 = __builtin_amdgcn_cvt_pkrtz(pe[o + 6], pe[o + 7]);
                ls0 = __builtin_amdgcn_fdot2(h0, one2, ls0, false);
                ls1 = __builtin_amdgcn_fdot2(h1, one2, ls1, false);
                ls0 = __builtin_amdgcn_fdot2(h2, one2, ls0, false);
                ls1 = __builtin_amdgcn_fdot2(h3, one2, ls1, false);
                u32 a0 = __builtin_bit_cast(u32, h0);
                u32 a1 = __builtin_bit_cast(u32, h1);
                u32 a2 = __builtin_bit_cast(u32, h2);
                u32 a3 = __builtin_bit_cast(u32, h3);
                asm volatile("v_permlane32_swap_b32 %0, %1" : "+v"(a0), "+v"(a2));
                asm volatile("v_permlane32_swap_b32 %0, %1" : "+v"(a1), "+v"(a3));
                W4 w;
                w.w[0] = a0; w.w[1] = a1; w.w[2] = a2; w.w[3] = a3;
                pa[kb * 2 + ks2] = w.v;
            }
        }

        // ---- PV ----
        __builtin_amdgcn_s_setprio(1);
#pragma unroll
        for (int nb = 0; nb < 2; ++nb)
#pragma unroll
            for (int ksg = 0; ksg < 4; ++ksg) {
                const f16x8 bv = *(const f16x8*)(Vc + lane16 + (nb * 4 + ksg) * 1024);
                accO[nb] = __builtin_amdgcn_mfma_f32_32x32x16_f16(pa[ksg], bv, accO[nb], 0, 0, 0);
            }
        __builtin_amdgcn_s_setprio(0);

        mfc0 = mfn0;
        mfc1 = mfn1;
        __syncthreads();
    }

    // ---- epilogue ----
    float lsum = ls0 + ls1;
    lsum += __shfl_xor(lsum, 32);
    const float linv = 1.0f / lsum;

    float lr[16];
#pragma unroll
    for (int r = 0; r < 16; ++r)
        lr[r] = __shfl(linv, (r & 3) + 8 * (r >> 2) + 4 * hi2);

#pragma unroll
    for (int nb = 0; nb < 2; ++nb) {
        const int dcol = h * HD + nb * 32 + l31;
#pragma unroll
        for (int r = 0; r < 16; ++r) {
            const int qrow = q0 + wid * 32 + (r & 3) + 8 * (r >> 2) + 4 * hi2;
            out[((size_t)b * S + qrow) * D + dcol] = accO[nb][r] * lr[r];
        }
    }
}

// ---------------------------------------------------------------------------
extern "C" void kernel_launch(void* const* d_in, const int* in_sizes, int n_in,
                              void* d_out, int out_size, void* d_ws, size_t ws_size,
                              hipStream_t stream)
{
    const float* q    = (const float*)d_in[0];
    const float* k    = (const float*)d_in[1];
    const float* v    = (const float*)d_in[2];
    const float* mask = (const float*)d_in[3];
    const float* wq   = (const float*)d_in[4];
    const float* bq   = (const float*)d_in[5];
    const float* wk   = (const float*)d_in[6];
    const float* bk   = (const float*)d_in[7];
    const float* wv   = (const float*)d_in[8];
    const float* bv   = (const float*)d_in[9];

    unsigned short* ws = (unsigned short*)d_ws;
    const size_t per  = (size_t)B * S * D;          // 8,388,608
    const size_t wsz  = 1048576;                    // one weight matrix (f16)
    const size_t mfsz = 131072;                     // mask-fragment table
    const size_t need = (3 * per + 3 * wsz + 3 * per + mfsz) * 2;

    dim3 ga(S / 128, B * H);
    if (ws_size >= need) {
        unsigned short* af16 = ws;
        unsigned short* wf16 = ws + 3 * per;
        unsigned short* outs = ws + 3 * per + 3 * wsz;
        unsigned short* mfp  = outs + 3 * per;
        mf_prep<<<64, 256, 0, stream>>>(mask, mfp);
        cvt_prep<<<13824, 256, 0, stream>>>(q, k, v, wq, wk, wv, af16);
        proj_f16<<<1536, 256, 0, stream>>>(af16, wf16, bq, bk, bv, outs);
        attn_f16<<<ga, 256, 0, stream>>>(outs, outs + per, outs + 2 * per, mfp, (float*)d_out);
    } else {
        unsigned short* mfp = ws + 3 * per;
        mf_prep<<<64, 256, 0, stream>>>(mask, mfp);
        proj_qkv<<<1536, 256, 0, stream>>>(q, k, v, wq, wk, wv, bq, bk, bv, ws);
        attn_f16<<<ga, 256, 0, stream>>>(ws, ws + per, ws + 2 * per, mfp, (float*)d_out);
    }
}

// Round 20
// 224.382 us; speedup vs baseline: 1.0249x; 1.0249x over previous
//
#include <hip/hip_runtime.h>
#include <math.h>

typedef __attribute__((ext_vector_type(8)))  _Float16 f16x8;
typedef __attribute__((ext_vector_type(4)))  _Float16 f16x4;
typedef __attribute__((ext_vector_type(2)))  __fp16   h16x2;   // cvt_pkrtz/fdot2 type
typedef __attribute__((ext_vector_type(4)))  float    f32x4;
typedef __attribute__((ext_vector_type(16))) float    f32x16;
typedef unsigned int u32;

static constexpr int B  = 4;
static constexpr int S  = 2048;
static constexpr int D  = 1024;
static constexpr int H  = 16;
static constexpr int HD = 64;

union U64cvt { f16x4 h; ushort4 u; };
union W4 { u32 w[4]; f16x8 v; };

__device__ __forceinline__ void gld16(const void* g, void* l) {
    // async global->LDS, 16B per lane; LDS dest = wave-uniform base + lane*16
    __builtin_amdgcn_global_load_lds((const u32*)g, (u32*)l, 16, 0, 0);
}

__device__ __forceinline__ void cvtwr16(const float4& x, const float4& y, void* dst) {
    W4 w;
    w.w[0] = __builtin_bit_cast(u32, __builtin_amdgcn_cvt_pkrtz(x.x, x.y));
    w.w[1] = __builtin_bit_cast(u32, __builtin_amdgcn_cvt_pkrtz(x.z, x.w));
    w.w[2] = __builtin_bit_cast(u32, __builtin_amdgcn_cvt_pkrtz(y.x, y.y));
    w.w[3] = __builtin_bit_cast(u32, __builtin_amdgcn_cvt_pkrtz(y.z, y.w));
    *(f16x8*)dst = w.v;
}

// ---------------------------------------------------------------------------
// Prepass: convert q,k,v + wq,wk,wv fp32 -> f16 row-major (memory-bound).
// ---------------------------------------------------------------------------
__global__ __launch_bounds__(256)
void cvt_prep(const float* __restrict__ q, const float* __restrict__ k,
              const float* __restrict__ v,
              const float* __restrict__ wq, const float* __restrict__ wk,
              const float* __restrict__ wv,
              unsigned short* __restrict__ dst)
{
    const int c = blockIdx.x * 256 + threadIdx.x;   // chunk id (8 elems)
    const float* src;
    size_t idx;
    if (c < 3145728) {
        const int a = c >> 20;
        src = (a == 0) ? q : (a == 1) ? k : v;
        idx = (size_t)(c & 1048575) * 8;
    } else {
        const int c2 = c - 3145728;
        const int a = c2 >> 17;
        src = (a == 0) ? wq : (a == 1) ? wk : wv;
        idx = (size_t)(c2 & 131071) * 8;
    }
    const float4 x = *(const float4*)(src + idx);
    const float4 y = *(const float4*)(src + idx + 4);
    cvtwr16(x, y, dst + (size_t)c * 8);
}

// ---------------------------------------------------------------------------
// f16 QKV projection, m97 structure: pure global_load_lds staging, double-
// buffered, one barrier per k-step, pre-swizzled source addresses.
//   z=0: Q head layout; z=1: K FRAGMENT-MAJOR; z=2: V FRAGMENT-MAJOR.
// ---------------------------------------------------------------------------
__global__ __launch_bounds__(256)
void proj_f16(const unsigned short* __restrict__ af16,
              const unsigned short* __restrict__ wf16,
              const float* __restrict__ bqp, const float* __restrict__ bkp,
              const float* __restrict__ bvp,
              unsigned short* __restrict__ outs)
{
    const int bid = blockIdx.x;
    const int xcd = bid & 7;
    const int idx = bid >> 3;
    const int z   = idx / 64;
    const int r2  = idx - z * 64;
    const int mpl = r2 >> 3;
    const int np  = r2 & 7;
    const int mp  = (xcd >> 1) * 16 + (xcd & 1) * 8 + mpl;
    const int m0  = mp * 128;
    const int n0  = np * 128;

    const unsigned short* A  = af16 + (size_t)z * 8388608;
    const unsigned short* Wf = wf16 + (size_t)z * 1048576;
    const float* bias = (z == 0) ? bqp : (z == 1) ? bkp : bvp;
    unsigned short* out = outs + (size_t)z * 8388608;

    const int tid  = threadIdx.x;
    const int lane = tid & 63;
    const int wid  = tid >> 6;
    const int wr   = wid >> 1;
    const int wc   = wid & 1;

    __shared__ __align__(16) unsigned char lA[2][8192];
    __shared__ __align__(16) unsigned char lB[2][8192];

    f32x4 acc[4][4];
#pragma unroll
    for (int i = 0; i < 4; ++i)
#pragma unroll
        for (int j = 0; j < 4; ++j) acc[i][j] = (f32x4){0.f, 0.f, 0.f, 0.f};

    int grow[2], gcol[2], lbase[2];
#pragma unroll
    for (int i = 0; i < 2; ++i) {
        const int c = tid + 256 * i;
        grow[i]  = c >> 2;
        gcol[i]  = ((c & 3) - (grow[i] >> 1)) & 3;
        lbase[i] = (c & ~63) * 16;
    }

#pragma unroll
    for (int i = 0; i < 2; ++i) {
        gld16(A  + (size_t)(m0 + grow[i]) * D + gcol[i] * 8, lA[0] + lbase[i]);
        gld16(Wf + (size_t)(n0 + grow[i]) * D + gcol[i] * 8, lB[0] + lbase[i]);
    }
    __syncthreads();

    for (int kt = 0; kt < 32; ++kt) {
        const int cb = kt & 1, nx = cb ^ 1;

        if (kt < 31) {
            const int k1 = (kt + 1) * 32;
#pragma unroll
            for (int i = 0; i < 2; ++i) {
                gld16(A  + (size_t)(m0 + grow[i]) * D + k1 + gcol[i] * 8, lA[nx] + lbase[i]);
                gld16(Wf + (size_t)(n0 + grow[i]) * D + k1 + gcol[i] * 8, lB[nx] + lbase[i]);
            }
        }

        f16x8 af[4], bf[4];
#pragma unroll
        for (int mi = 0; mi < 4; ++mi) {
            const int row = wr * 64 + mi * 16 + (lane & 15);
            const int cc  = ((lane >> 4) + (row >> 1)) & 3;
            af[mi] = *(const f16x8*)(lA[cb] + row * 64 + cc * 16);
        }
#pragma unroll
        for (int ni = 0; ni < 4; ++ni) {
            const int row = wc * 64 + ni * 16 + (lane & 15);
            const int cc  = ((lane >> 4) + (row >> 1)) & 3;
            bf[ni] = *(const f16x8*)(lB[cb] + row * 64 + cc * 16);
        }

        __builtin_amdgcn_s_setprio(1);
#pragma unroll
        for (int mi = 0; mi < 4; ++mi)
#pragma unroll
            for (int ni = 0; ni < 4; ++ni)
                acc[mi][ni] = __builtin_amdgcn_mfma_f32_16x16x32_f16(af[mi], bf[ni], acc[mi][ni], 0, 0, 0);
        __builtin_amdgcn_s_setprio(0);

        __syncthreads();
    }

#pragma unroll
    for (int mi = 0; mi < 4; ++mi) {
        const int gmBase = m0 + wr * 64 + mi * 16 + ((lane >> 4) << 2);
        const int b  = gmBase >> 11;
        const int s0 = gmBase & 2047;
        const int tV   = s0 >> 6;
        const int kv6  = s0 & 63;
        const int ksg  = kv6 >> 4;
        const int hi2v = (kv6 >> 3) & 1;
        const int jb   = kv6 & 7;
#pragma unroll
        for (int ni = 0; ni < 4; ++ni) {
            const int gn = n0 + wc * 64 + ni * 16 + (lane & 15);
            const float bb = bias[gn];
            const int hh = gn >> 6;
            const int hd = gn & 63;
            const size_t bhbase = ((size_t)b * H + hh) * ((size_t)S * HD);
            if (z == 0) {
#pragma unroll
                for (int r = 0; r < 4; ++r) {
                    const int gm = gmBase + r;
                    const _Float16 hv = (_Float16)(acc[mi][ni][r] + bb);
                    out[bhbase + (size_t)(gm & 2047) * HD + hd] =
                        __builtin_bit_cast(unsigned short, hv);
                }
            } else if (z == 1) {
                const int ks   = hd >> 4;
                const int hi2k = (hd >> 3) & 1;
                const int j    = hd & 7;
#pragma unroll
                for (int r = 0; r < 4; ++r) {
                    const int s = (gmBase + r) & 2047;
                    const int t = s >> 6;
                    const int q = ((s >> 5) & 1) * 4 + ks;
                    const _Float16 hv = (_Float16)(acc[mi][ni][r] + bb);
                    out[bhbase + (((size_t)t * 8 + q) * 64 + hi2k * 32 + (s & 31)) * 8 + j] =
                        __builtin_bit_cast(unsigned short, hv);
                }
            } else {
                const int nb  = hd >> 5;
                const int c31 = hd & 31;
                const int q   = nb * 4 + ksg;
                U64cvt uu;
#pragma unroll
                for (int r = 0; r < 4; ++r)
                    uu.h[r] = (_Float16)(acc[mi][ni][r] + bb);
                *(ushort4*)(out + bhbase +
                    (((size_t)tV * 8 + q) * 64 + hi2v * 32 + c31) * 8 + jb) = uu.u;
            }
        }
    }
}

// ---------------------------------------------------------------------------
// FALLBACK projection (fp32 reg-staging) if ws is too small.
// ---------------------------------------------------------------------------
__global__ __launch_bounds__(256)
void proj_qkv(const float* __restrict__ qi, const float* __restrict__ ki,
              const float* __restrict__ vi,
              const float* __restrict__ wqp, const float* __restrict__ wkp,
              const float* __restrict__ wvp,
              const float* __restrict__ bqp, const float* __restrict__ bkp,
              const float* __restrict__ bvp,
              unsigned short* __restrict__ ws)
{
    const int bid = blockIdx.x;
    const int xcd = bid & 7;
    const int idx = bid >> 3;
    const int z   = idx / 64;
    const int r2  = idx - z * 64;
    const int mpl = r2 >> 3;
    const int np  = r2 & 7;
    const int mp  = (xcd >> 1) * 16 + (xcd & 1) * 8 + mpl;
    const int m0  = mp * 128;
    const int n0  = np * 128;

    const float* A    = (z == 0) ? qi  : (z == 1) ? ki  : vi;
    const float* W    = (z == 0) ? wqp : (z == 1) ? wkp : wvp;
    const float* bias = (z == 0) ? bqp : (z == 1) ? bkp : bvp;
    unsigned short* out = ws + (size_t)z * ((size_t)B * S * D);

    const int tid  = threadIdx.x;
    const int lane = tid & 63;
    const int wid  = tid >> 6;
    const int wr   = wid >> 1;
    const int wc   = wid & 1;

    __shared__ __align__(16) unsigned char lA[2][8192];
    __shared__ __align__(16) unsigned char lB[2][8192];

    f32x4 acc[4][4];
#pragma unroll
    for (int i = 0; i < 4; ++i)
#pragma unroll
        for (int j = 0; j < 4; ++j) acc[i][j] = (f32x4){0.f, 0.f, 0.f, 0.f};

    const int rb = (lane >> 4) * 16;

    int srow[2], sc8[2], soff[2];
#pragma unroll
    for (int i = 0; i < 2; ++i) {
        const int f = tid + 256 * i;
        srow[i] = f >> 2;
        sc8[i]  = f & 3;
        soff[i] = ((f >> 2) * 64 + (f & 3) * 16) ^ ((((f >> 2)) & 7) << 4);
    }

#pragma unroll
    for (int i = 0; i < 2; ++i) {
        const float* pa = A + (size_t)(m0 + srow[i]) * D + sc8[i] * 8;
        const float* pw = W + (size_t)(n0 + srow[i]) * D + sc8[i] * 8;
        cvtwr16(*(const float4*)pa, *(const float4*)(pa + 4), lA[0] + soff[i]);
        cvtwr16(*(const float4*)pw, *(const float4*)(pw + 4), lB[0] + soff[i]);
    }
    float4 pa0[2], pa1[2], pw0[2], pw1[2];
#pragma unroll
    for (int i = 0; i < 2; ++i) {
        const float* pa = A + (size_t)(m0 + srow[i]) * D + 32 + sc8[i] * 8;
        const float* pw = W + (size_t)(n0 + srow[i]) * D + 32 + sc8[i] * 8;
        pa0[i] = *(const float4*)pa;  pa1[i] = *(const float4*)(pa + 4);
        pw0[i] = *(const float4*)pw;  pw1[i] = *(const float4*)(pw + 4);
    }
    __syncthreads();

    for (int kt = 0; kt < 32; ++kt) {
        const int cb = kt & 1, nx = cb ^ 1;
        if (kt < 31) {
#pragma unroll
            for (int i = 0; i < 2; ++i) {
                cvtwr16(pa0[i], pa1[i], lA[nx] + soff[i]);
                cvtwr16(pw0[i], pw1[i], lB[nx] + soff[i]);
            }
        }
        f16x8 af[4], bf[4];
#pragma unroll
        for (int mi = 0; mi < 4; ++mi) {
            const int row = wr * 64 + mi * 16 + (lane & 15);
            af[mi] = *(const f16x8*)(lA[cb] + ((row * 64 + rb) ^ ((row & 7) << 4)));
        }
#pragma unroll
        for (int ni = 0; ni < 4; ++ni) {
            const int row = wc * 64 + ni * 16 + (lane & 15);
            bf[ni] = *(const f16x8*)(lB[cb] + ((row * 64 + rb) ^ ((row & 7) << 4)));
        }
        if (kt < 30) {
            const int k2 = (kt + 2) * 32;
#pragma unroll
            for (int i = 0; i < 2; ++i) {
                const float* pa = A + (size_t)(m0 + srow[i]) * D + k2 + sc8[i] * 8;
                const float* pw = W + (size_t)(n0 + srow[i]) * D + k2 + sc8[i] * 8;
                pa0[i] = *(const float4*)pa;  pa1[i] = *(const float4*)(pa + 4);
                pw0[i] = *(const float4*)pw;  pw1[i] = *(const float4*)(pw + 4);
            }
        }
        __builtin_amdgcn_s_setprio(1);
#pragma unroll
        for (int mi = 0; mi < 4; ++mi)
#pragma unroll
            for (int ni = 0; ni < 4; ++ni)
                acc[mi][ni] = __builtin_amdgcn_mfma_f32_16x16x32_f16(af[mi], bf[ni], acc[mi][ni], 0, 0, 0);
        __builtin_amdgcn_s_setprio(0);
        __syncthreads();
    }

#pragma unroll
    for (int mi = 0; mi < 4; ++mi) {
        const int gmBase = m0 + wr * 64 + mi * 16 + ((lane >> 4) << 2);
        const int b  = gmBase >> 11;
        const int s0 = gmBase & 2047;
        const int tV   = s0 >> 6;
        const int kv6  = s0 & 63;
        const int ksg  = kv6 >> 4;
        const int hi2v = (kv6 >> 3) & 1;
        const int jb   = kv6 & 7;
#pragma unroll
        for (int ni = 0; ni < 4; ++ni) {
            const int gn = n0 + wc * 64 + ni * 16 + (lane & 15);
            const float bb = bias[gn];
            const int hh = gn >> 6;
            const int hd = gn & 63;
            const size_t bhbase = ((size_t)b * H + hh) * ((size_t)S * HD);
            if (z == 0) {
#pragma unroll
                for (int r = 0; r < 4; ++r) {
                    const int gm = gmBase + r;
                    const _Float16 hv = (_Float16)(acc[mi][ni][r] + bb);
                    out[bhbase + (size_t)(gm & 2047) * HD + hd] =
                        __builtin_bit_cast(unsigned short, hv);
                }
            } else if (z == 1) {
                const int ks   = hd >> 4;
                const int hi2k = (hd >> 3) & 1;
                const int j    = hd & 7;
#pragma unroll
                for (int r = 0; r < 4; ++r) {
                    const int s = (gmBase + r) & 2047;
                    const int t = s >> 6;
                    const int q = ((s >> 5) & 1) * 4 + ks;
                    const _Float16 hv = (_Float16)(acc[mi][ni][r] + bb);
                    out[bhbase + (((size_t)t * 8 + q) * 64 + hi2k * 32 + (s & 31)) * 8 + j] =
                        __builtin_bit_cast(unsigned short, hv);
                }
            } else {
                const int nb  = hd >> 5;
                const int c31 = hd & 31;
                const int q   = nb * 4 + ksg;
                U64cvt uu;
#pragma unroll
                for (int r = 0; r < 4; ++r)
                    uu.h[r] = (_Float16)(acc[mi][ni][r] + bb);
                *(ushort4*)(out + bhbase +
                    (((size_t)tV * 8 + q) * 64 + hi2v * 32 + c31) * 8 + jb) = uu.u;
            }
        }
    }
}

// ---------------------------------------------------------------------------
// Flash attention fwd (r18 + KVBLK=128): fragment-major K/V, gld16 staging,
// double-buffered 128-kv tiles processed as two sequential 64-kv halves
// (p/pa registers reused -> VGPR identical to r18), ONE barrier per 128 kv
// (half the barrier/drain overhead). Lane-local no-max softmax; in-register
// P->A-frag (cvt_pkrtz + permlane32); lsum via fdot2.
// ---------------------------------------------------------------------------
__global__ __launch_bounds__(256)
void attn_f16(const unsigned short* __restrict__ qh,
              const unsigned short* __restrict__ kf,
              const unsigned short* __restrict__ vf,
              const float* __restrict__ mask,
              float* __restrict__ out)
{
    // bijective XCD swizzle: XCD x covers bh in [x*8, x*8+8) -> b = x>>1
    const int flat = blockIdx.y * gridDim.x + blockIdx.x;   // 0..1023
    const int sw   = (flat & 7) * 128 + (flat >> 3);
    const int bh   = sw >> 4;
    const int q0   = (sw & 15) * 128;

    const int b = bh >> 4;
    const int h = bh & 15;
    const unsigned short* Q  = qh + (size_t)bh * S * HD;
    const unsigned short* KF = kf + (size_t)bh * S * HD;   // frag-major
    const unsigned short* VF = vf + (size_t)bh * S * HD;   // frag-major

    const int tid  = threadIdx.x;
    const int lane = tid & 63;
    const int wid  = tid >> 6;
    const int l31  = lane & 31;
    const int hi2  = lane >> 5;

    __shared__ __align__(16) unsigned char Kl[2][16384];   // fragment-major, 128 kv
    __shared__ __align__(16) unsigned char Vl[2][16384];
    __shared__ __align__(16) float maskb[2][128];

    const int ldsW = wid * 1024;     // wave-uniform LDS sub-base
    const int g0   = tid * 8;        // elem offset of this thread's chunk

    const float C = 0.18033688011112042f;          // 0.125 * log2(e)
    const float SHIFT = -5.770780163555854f;       // -4 * log2(e)

    // hoist Q as the B-operand: col = l31, k = hi2*8 + j (+16*ks)
    f16x8 aq[4];
    {
        const unsigned short* qrow = Q + (size_t)(q0 + wid * 32 + l31) * HD;
#pragma unroll
        for (int ks = 0; ks < 4; ++ks)
            aq[ks] = *(const f16x8*)(qrow + ks * 16 + hi2 * 8);
    }

    float ls0 = 0.f, ls1 = 0.f;
    f32x16 accO[2];
    accO[0] = (f32x16){};
    accO[1] = (f32x16){};
    const h16x2 one2 = {(__fp16)1.0f, (__fp16)1.0f};

    // ---- prologue: stage 128-kv tile 0 into buf 0 ----
#pragma unroll
    for (int i = 0; i < 4; ++i) {
        gld16(KF + i * 2048 + g0, Kl[0] + i * 4096 + ldsW);
        gld16(VF + i * 2048 + g0, Vl[0] + i * 4096 + ldsW);
    }
    if (tid < 128)
        maskb[0][tid] = fmaf(1.0f - mask[(size_t)b * S + tid], -1.4426950408889634e30f, SHIFT);
    __syncthreads();

    const int lane16 = lane * 16;
    for (int t = 0; t < S / 128; ++t) {
        const int cb = t & 1, nx = cb ^ 1;
        const unsigned char* Kc = Kl[cb];
        const unsigned char* Vc = Vl[cb];

        // ---- stage next 128-kv tile FIRST (buffer nx dead since prev barrier) ----
        if (t < S / 128 - 1) {
            const size_t nt = (size_t)(t + 1) * 8192;
#pragma unroll
            for (int i = 0; i < 4; ++i) {
                gld16(KF + nt + i * 2048 + g0, Kl[nx] + i * 4096 + ldsW);
                gld16(VF + nt + i * 2048 + g0, Vl[nx] + i * 4096 + ldsW);
            }
            if (tid < 128)
                maskb[nx][tid] = fmaf(1.0f - mask[(size_t)b * S + (t + 1) * 128 + tid],
                                      -1.4426950408889634e30f, SHIFT);
        }

        // ---- two 64-kv halves, registers reused across halves ----
#pragma unroll
        for (int half = 0; half < 2; ++half) {
            const int hofs = half * 8192;

            // QK^T (swapped): p[kb] = K x Q, col = q, row = kv
            f32x16 p[2];
            p[0] = (f32x16){};
            p[1] = (f32x16){};
            __builtin_amdgcn_s_setprio(1);
#pragma unroll
            for (int kb = 0; kb < 2; ++kb)
#pragma unroll
                for (int ks = 0; ks < 4; ++ks) {
                    const f16x8 ak = *(const f16x8*)(Kc + hofs + lane16 + (kb * 4 + ks) * 1024);
                    p[kb] = __builtin_amdgcn_mfma_f32_32x32x16_f16(ak, aq[ks], p[kb], 0, 0, 0);
                }
            __builtin_amdgcn_s_setprio(0);

            // lane-local softmax + in-register P->A-frag
            f16x8 pa[4];
#pragma unroll
            for (int kb = 0; kb < 2; ++kb) {
                float pe[16];
#pragma unroll
                for (int g = 0; g < 4; ++g) {
                    const f32x4 mg = *(const f32x4*)(&maskb[cb][half * 64 + kb * 32 + g * 8 + hi2 * 4]);
#pragma unroll
                    for (int e = 0; e < 4; ++e)
                        pe[g * 4 + e] = exp2f(fmaf(p[kb][g * 4 + e], C, mg[e]));
                }
#pragma unroll
                for (int ks2 = 0; ks2 < 2; ++ks2) {
                    const int o = ks2 * 8;
                    const h16x2 h0 = __builtin_amdgcn_cvt_pkrtz(pe[o + 0], pe[o + 1]);
                    const h16x2 h1 = __builtin_amdgcn_cvt_pkrtz(pe[o + 2], pe[o + 3]);
                    const h16x2 h2 = __builtin_amdgcn_cvt_pkrtz(pe[o + 4], pe[o + 5]);
                    const h16x2 h3 = __builtin_amdgcn_cvt_pkrtz(pe[o + 6], pe[o + 7]);
                    ls0 = __builtin_amdgcn_fdot2(h0, one2, ls0, false);
                    ls1 = __builtin_amdgcn_fdot2(h1, one2, ls1, false);
                    ls0 = __builtin_amdgcn_fdot2(h2, one2, ls0, false);
                    ls1 = __builtin_amdgcn_fdot2(h3, one2, ls1, false);
                    u32 a0 = __builtin_bit_cast(u32, h0);
                    u32 a1 = __builtin_bit_cast(u32, h1);
                    u32 a2 = __builtin_bit_cast(u32, h2);
                    u32 a3 = __builtin_bit_cast(u32, h3);
                    asm volatile("v_permlane32_swap_b32 %0, %1" : "+v"(a0), "+v"(a2));
                    asm volatile("v_permlane32_swap_b32 %0, %1" : "+v"(a1), "+v"(a3));
                    W4 w;
                    w.w[0] = a0; w.w[1] = a1; w.w[2] = a2; w.w[3] = a3;
                    pa[kb * 2 + ks2] = w.v;
                }
            }

            // PV: accO[nb] += P x V
            __builtin_amdgcn_s_setprio(1);
#pragma unroll
            for (int nb = 0; nb < 2; ++nb)
#pragma unroll
                for (int ksg = 0; ksg < 4; ++ksg) {
                    const f16x8 bv = *(const f16x8*)(Vc + hofs + lane16 + (nb * 4 + ksg) * 1024);
                    accO[nb] = __builtin_amdgcn_mfma_f32_32x32x16_f16(pa[ksg], bv, accO[nb], 0, 0, 0);
                }
            __builtin_amdgcn_s_setprio(0);
        }

        __syncthreads();   // drains vmcnt: next 128-kv buffer ready
    }

    // ---- epilogue: finish lsum (one xor-32), redistribute 1/l, store ----
    float lsum = ls0 + ls1;
    lsum += __shfl_xor(lsum, 32);
    const float linv = 1.0f / lsum;

    float lr[16];
#pragma unroll
    for (int r = 0; r < 16; ++r)
        lr[r] = __shfl(linv, (r & 3) + 8 * (r >> 2) + 4 * hi2);

#pragma unroll
    for (int nb = 0; nb < 2; ++nb) {
        const int dcol = h * HD + nb * 32 + l31;
#pragma unroll
        for (int r = 0; r < 16; ++r) {
            const int qrow = q0 + wid * 32 + (r & 3) + 8 * (r >> 2) + 4 * hi2;
            out[((size_t)b * S + qrow) * D + dcol] = accO[nb][r] * lr[r];
        }
    }
}

// ---------------------------------------------------------------------------
extern "C" void kernel_launch(void* const* d_in, const int* in_sizes, int n_in,
                              void* d_out, int out_size, void* d_ws, size_t ws_size,
                              hipStream_t stream)
{
    const float* q    = (const float*)d_in[0];
    const float* k    = (const float*)d_in[1];
    const float* v    = (const float*)d_in[2];
    const float* mask = (const float*)d_in[3];
    const float* wq   = (const float*)d_in[4];
    const float* bq   = (const float*)d_in[5];
    const float* wk   = (const float*)d_in[6];
    const float* bk   = (const float*)d_in[7];
    const float* wv   = (const float*)d_in[8];
    const float* bv   = (const float*)d_in[9];

    unsigned short* ws = (unsigned short*)d_ws;
    const size_t per  = (size_t)B * S * D;          // 8,388,608
    const size_t wsz  = 1048576;                    // one weight matrix (f16)
    const size_t need = (3 * per + 3 * wsz + 3 * per) * 2;

    dim3 ga(S / 128, B * H);
    if (ws_size >= need) {
        unsigned short* af16 = ws;
        unsigned short* wf16 = ws + 3 * per;
        unsigned short* outs = ws + 3 * per + 3 * wsz;
        cvt_prep<<<13824, 256, 0, stream>>>(q, k, v, wq, wk, wv, af16);
        proj_f16<<<1536, 256, 0, stream>>>(af16, wf16, bq, bk, bv, outs);
        attn_f16<<<ga, 256, 0, stream>>>(outs, outs + per, outs + 2 * per, mask, (float*)d_out);
    } else {
        proj_qkv<<<1536, 256, 0, stream>>>(q, k, v, wq, wk, wv, bq, bk, bv, ws);
        attn_f16<<<ga, 256, 0, stream>>>(ws, ws + per, ws + 2 * per, mask, (float*)d_out);
    }
}

// Round 21
// 206.408 us; speedup vs baseline: 1.1141x; 1.0871x over previous
//
#include <hip/hip_runtime.h>
#include <math.h>

typedef __attribute__((ext_vector_type(8)))  _Float16 f16x8;
typedef __attribute__((ext_vector_type(4)))  _Float16 f16x4;
typedef __attribute__((ext_vector_type(2)))  __fp16   h16x2;   // cvt_pkrtz/fdot2 type
typedef __attribute__((ext_vector_type(4)))  float    f32x4;
typedef __attribute__((ext_vector_type(16))) float    f32x16;
typedef unsigned int u32;

static constexpr int B  = 4;
static constexpr int S  = 2048;
static constexpr int D  = 1024;
static constexpr int H  = 16;
static constexpr int HD = 64;

union U64cvt { f16x4 h; ushort4 u; };
union W4 { u32 w[4]; f16x8 v; };

__device__ __forceinline__ void gld16(const void* g, void* l) {
    // async global->LDS, 16B per lane; LDS dest = wave-uniform base + lane*16
    __builtin_amdgcn_global_load_lds((const u32*)g, (u32*)l, 16, 0, 0);
}

__device__ __forceinline__ void cvtwr16(const float4& x, const float4& y, void* dst) {
    W4 w;
    w.w[0] = __builtin_bit_cast(u32, __builtin_amdgcn_cvt_pkrtz(x.x, x.y));
    w.w[1] = __builtin_bit_cast(u32, __builtin_amdgcn_cvt_pkrtz(x.z, x.w));
    w.w[2] = __builtin_bit_cast(u32, __builtin_amdgcn_cvt_pkrtz(y.x, y.y));
    w.w[3] = __builtin_bit_cast(u32, __builtin_amdgcn_cvt_pkrtz(y.z, y.w));
    *(f16x8*)dst = w.v;
}

// ---------------------------------------------------------------------------
// Prepass: convert q,k,v + wq,wk,wv fp32 -> f16 row-major (memory-bound).
// ---------------------------------------------------------------------------
__global__ __launch_bounds__(256)
void cvt_prep(const float* __restrict__ q, const float* __restrict__ k,
              const float* __restrict__ v,
              const float* __restrict__ wq, const float* __restrict__ wk,
              const float* __restrict__ wv,
              unsigned short* __restrict__ dst)
{
    const int c = blockIdx.x * 256 + threadIdx.x;   // chunk id (8 elems)
    const float* src;
    size_t idx;
    if (c < 3145728) {
        const int a = c >> 20;
        src = (a == 0) ? q : (a == 1) ? k : v;
        idx = (size_t)(c & 1048575) * 8;
    } else {
        const int c2 = c - 3145728;
        const int a = c2 >> 17;
        src = (a == 0) ? wq : (a == 1) ? wk : wv;
        idx = (size_t)(c2 & 131071) * 8;
    }
    const float4 x = *(const float4*)(src + idx);
    const float4 y = *(const float4*)(src + idx + 4);
    cvtwr16(x, y, dst + (size_t)c * 8);
}

// ---------------------------------------------------------------------------
// f16 QKV projection, m97 structure: pure global_load_lds staging, double-
// buffered, one barrier per k-step, pre-swizzled source addresses.
//   z=0: Q head layout; z=1: K FRAGMENT-MAJOR; z=2: V FRAGMENT-MAJOR.
// ---------------------------------------------------------------------------
__global__ __launch_bounds__(256)
void proj_f16(const unsigned short* __restrict__ af16,
              const unsigned short* __restrict__ wf16,
              const float* __restrict__ bqp, const float* __restrict__ bkp,
              const float* __restrict__ bvp,
              unsigned short* __restrict__ outs)
{
    const int bid = blockIdx.x;
    const int xcd = bid & 7;
    const int idx = bid >> 3;
    const int z   = idx / 64;
    const int r2  = idx - z * 64;
    const int mpl = r2 >> 3;
    const int np  = r2 & 7;
    const int mp  = (xcd >> 1) * 16 + (xcd & 1) * 8 + mpl;
    const int m0  = mp * 128;
    const int n0  = np * 128;

    const unsigned short* A  = af16 + (size_t)z * 8388608;
    const unsigned short* Wf = wf16 + (size_t)z * 1048576;
    const float* bias = (z == 0) ? bqp : (z == 1) ? bkp : bvp;
    unsigned short* out = outs + (size_t)z * 8388608;

    const int tid  = threadIdx.x;
    const int lane = tid & 63;
    const int wid  = tid >> 6;
    const int wr   = wid >> 1;
    const int wc   = wid & 1;

    __shared__ __align__(16) unsigned char lA[2][8192];
    __shared__ __align__(16) unsigned char lB[2][8192];

    f32x4 acc[4][4];
#pragma unroll
    for (int i = 0; i < 4; ++i)
#pragma unroll
        for (int j = 0; j < 4; ++j) acc[i][j] = (f32x4){0.f, 0.f, 0.f, 0.f};

    int grow[2], gcol[2], lbase[2];
#pragma unroll
    for (int i = 0; i < 2; ++i) {
        const int c = tid + 256 * i;
        grow[i]  = c >> 2;
        gcol[i]  = ((c & 3) - (grow[i] >> 1)) & 3;
        lbase[i] = (c & ~63) * 16;
    }

#pragma unroll
    for (int i = 0; i < 2; ++i) {
        gld16(A  + (size_t)(m0 + grow[i]) * D + gcol[i] * 8, lA[0] + lbase[i]);
        gld16(Wf + (size_t)(n0 + grow[i]) * D + gcol[i] * 8, lB[0] + lbase[i]);
    }
    __syncthreads();

    for (int kt = 0; kt < 32; ++kt) {
        const int cb = kt & 1, nx = cb ^ 1;

        if (kt < 31) {
            const int k1 = (kt + 1) * 32;
#pragma unroll
            for (int i = 0; i < 2; ++i) {
                gld16(A  + (size_t)(m0 + grow[i]) * D + k1 + gcol[i] * 8, lA[nx] + lbase[i]);
                gld16(Wf + (size_t)(n0 + grow[i]) * D + k1 + gcol[i] * 8, lB[nx] + lbase[i]);
            }
        }

        f16x8 af[4], bf[4];
#pragma unroll
        for (int mi = 0; mi < 4; ++mi) {
            const int row = wr * 64 + mi * 16 + (lane & 15);
            const int cc  = ((lane >> 4) + (row >> 1)) & 3;
            af[mi] = *(const f16x8*)(lA[cb] + row * 64 + cc * 16);
        }
#pragma unroll
        for (int ni = 0; ni < 4; ++ni) {
            const int row = wc * 64 + ni * 16 + (lane & 15);
            const int cc  = ((lane >> 4) + (row >> 1)) & 3;
            bf[ni] = *(const f16x8*)(lB[cb] + row * 64 + cc * 16);
        }

        __builtin_amdgcn_s_setprio(1);
#pragma unroll
        for (int mi = 0; mi < 4; ++mi)
#pragma unroll
            for (int ni = 0; ni < 4; ++ni)
                acc[mi][ni] = __builtin_amdgcn_mfma_f32_16x16x32_f16(af[mi], bf[ni], acc[mi][ni], 0, 0, 0);
        __builtin_amdgcn_s_setprio(0);

        __syncthreads();
    }

#pragma unroll
    for (int mi = 0; mi < 4; ++mi) {
        const int gmBase = m0 + wr * 64 + mi * 16 + ((lane >> 4) << 2);
        const int b  = gmBase >> 11;
        const int s0 = gmBase & 2047;
        const int tV   = s0 >> 6;
        const int kv6  = s0 & 63;
        const int ksg  = kv6 >> 4;
        const int hi2v = (kv6 >> 3) & 1;
        const int jb   = kv6 & 7;
#pragma unroll
        for (int ni = 0; ni < 4; ++ni) {
            const int gn = n0 + wc * 64 + ni * 16 + (lane & 15);
            const float bb = bias[gn];
            const int hh = gn >> 6;
            const int hd = gn & 63;
            const size_t bhbase = ((size_t)b * H + hh) * ((size_t)S * HD);
            if (z == 0) {
#pragma unroll
                for (int r = 0; r < 4; ++r) {
                    const int gm = gmBase + r;
                    const _Float16 hv = (_Float16)(acc[mi][ni][r] + bb);
                    out[bhbase + (size_t)(gm & 2047) * HD + hd] =
                        __builtin_bit_cast(unsigned short, hv);
                }
            } else if (z == 1) {
                const int ks   = hd >> 4;
                const int hi2k = (hd >> 3) & 1;
                const int j    = hd & 7;
#pragma unroll
                for (int r = 0; r < 4; ++r) {
                    const int s = (gmBase + r) & 2047;
                    const int t = s >> 6;
                    const int q = ((s >> 5) & 1) * 4 + ks;
                    const _Float16 hv = (_Float16)(acc[mi][ni][r] + bb);
                    out[bhbase + (((size_t)t * 8 + q) * 64 + hi2k * 32 + (s & 31)) * 8 + j] =
                        __builtin_bit_cast(unsigned short, hv);
                }
            } else {
                const int nb  = hd >> 5;
                const int c31 = hd & 31;
                const int q   = nb * 4 + ksg;
                U64cvt uu;
#pragma unroll
                for (int r = 0; r < 4; ++r)
                    uu.h[r] = (_Float16)(acc[mi][ni][r] + bb);
                *(ushort4*)(out + bhbase +
                    (((size_t)tV * 8 + q) * 64 + hi2v * 32 + c31) * 8 + jb) = uu.u;
            }
        }
    }
}

// ---------------------------------------------------------------------------
// FALLBACK projection (fp32 reg-staging) if ws is too small.
// ---------------------------------------------------------------------------
__global__ __launch_bounds__(256)
void proj_qkv(const float* __restrict__ qi, const float* __restrict__ ki,
              const float* __restrict__ vi,
              const float* __restrict__ wqp, const float* __restrict__ wkp,
              const float* __restrict__ wvp,
              const float* __restrict__ bqp, const float* __restrict__ bkp,
              const float* __restrict__ bvp,
              unsigned short* __restrict__ ws)
{
    const int bid = blockIdx.x;
    const int xcd = bid & 7;
    const int idx = bid >> 3;
    const int z   = idx / 64;
    const int r2  = idx - z * 64;
    const int mpl = r2 >> 3;
    const int np  = r2 & 7;
    const int mp  = (xcd >> 1) * 16 + (xcd & 1) * 8 + mpl;
    const int m0  = mp * 128;
    const int n0  = np * 128;

    const float* A    = (z == 0) ? qi  : (z == 1) ? ki  : vi;
    const float* W    = (z == 0) ? wqp : (z == 1) ? wkp : wvp;
    const float* bias = (z == 0) ? bqp : (z == 1) ? bkp : bvp;
    unsigned short* out = ws + (size_t)z * ((size_t)B * S * D);

    const int tid  = threadIdx.x;
    const int lane = tid & 63;
    const int wid  = tid >> 6;
    const int wr   = wid >> 1;
    const int wc   = wid & 1;

    __shared__ __align__(16) unsigned char lA[2][8192];
    __shared__ __align__(16) unsigned char lB[2][8192];

    f32x4 acc[4][4];
#pragma unroll
    for (int i = 0; i < 4; ++i)
#pragma unroll
        for (int j = 0; j < 4; ++j) acc[i][j] = (f32x4){0.f, 0.f, 0.f, 0.f};

    const int rb = (lane >> 4) * 16;

    int srow[2], sc8[2], soff[2];
#pragma unroll
    for (int i = 0; i < 2; ++i) {
        const int f = tid + 256 * i;
        srow[i] = f >> 2;
        sc8[i]  = f & 3;
        soff[i] = ((f >> 2) * 64 + (f & 3) * 16) ^ ((((f >> 2)) & 7) << 4);
    }

#pragma unroll
    for (int i = 0; i < 2; ++i) {
        const float* pa = A + (size_t)(m0 + srow[i]) * D + sc8[i] * 8;
        const float* pw = W + (size_t)(n0 + srow[i]) * D + sc8[i] * 8;
        cvtwr16(*(const float4*)pa, *(const float4*)(pa + 4), lA[0] + soff[i]);
        cvtwr16(*(const float4*)pw, *(const float4*)(pw + 4), lB[0] + soff[i]);
    }
    float4 pa0[2], pa1[2], pw0[2], pw1[2];
#pragma unroll
    for (int i = 0; i < 2; ++i) {
        const float* pa = A + (size_t)(m0 + srow[i]) * D + 32 + sc8[i] * 8;
        const float* pw = W + (size_t)(n0 + srow[i]) * D + 32 + sc8[i] * 8;
        pa0[i] = *(const float4*)pa;  pa1[i] = *(const float4*)(pa + 4);
        pw0[i] = *(const float4*)pw;  pw1[i] = *(const float4*)(pw + 4);
    }
    __syncthreads();

    for (int kt = 0; kt < 32; ++kt) {
        const int cb = kt & 1, nx = cb ^ 1;
        if (kt < 31) {
#pragma unroll
            for (int i = 0; i < 2; ++i) {
                cvtwr16(pa0[i], pa1[i], lA[nx] + soff[i]);
                cvtwr16(pw0[i], pw1[i], lB[nx] + soff[i]);
            }
        }
        f16x8 af[4], bf[4];
#pragma unroll
        for (int mi = 0; mi < 4; ++mi) {
            const int row = wr * 64 + mi * 16 + (lane & 15);
            af[mi] = *(const f16x8*)(lA[cb] + ((row * 64 + rb) ^ ((row & 7) << 4)));
        }
#pragma unroll
        for (int ni = 0; ni < 4; ++ni) {
            const int row = wc * 64 + ni * 16 + (lane & 15);
            bf[ni] = *(const f16x8*)(lB[cb] + ((row * 64 + rb) ^ ((row & 7) << 4)));
        }
        if (kt < 30) {
            const int k2 = (kt + 2) * 32;
#pragma unroll
            for (int i = 0; i < 2; ++i) {
                const float* pa = A + (size_t)(m0 + srow[i]) * D + k2 + sc8[i] * 8;
                const float* pw = W + (size_t)(n0 + srow[i]) * D + k2 + sc8[i] * 8;
                pa0[i] = *(const float4*)pa;  pa1[i] = *(const float4*)(pa + 4);
                pw0[i] = *(const float4*)pw;  pw1[i] = *(const float4*)(pw + 4);
            }
        }
        __builtin_amdgcn_s_setprio(1);
#pragma unroll
        for (int mi = 0; mi < 4; ++mi)
#pragma unroll
            for (int ni = 0; ni < 4; ++ni)
                acc[mi][ni] = __builtin_amdgcn_mfma_f32_16x16x32_f16(af[mi], bf[ni], acc[mi][ni], 0, 0, 0);
        __builtin_amdgcn_s_setprio(0);
        __syncthreads();
    }

#pragma unroll
    for (int mi = 0; mi < 4; ++mi) {
        const int gmBase = m0 + wr * 64 + mi * 16 + ((lane >> 4) << 2);
        const int b  = gmBase >> 11;
        const int s0 = gmBase & 2047;
        const int tV   = s0 >> 6;
        const int kv6  = s0 & 63;
        const int ksg  = kv6 >> 4;
        const int hi2v = (kv6 >> 3) & 1;
        const int jb   = kv6 & 7;
#pragma unroll
        for (int ni = 0; ni < 4; ++ni) {
            const int gn = n0 + wc * 64 + ni * 16 + (lane & 15);
            const float bb = bias[gn];
            const int hh = gn >> 6;
            const int hd = gn & 63;
            const size_t bhbase = ((size_t)b * H + hh) * ((size_t)S * HD);
            if (z == 0) {
#pragma unroll
                for (int r = 0; r < 4; ++r) {
                    const int gm = gmBase + r;
                    const _Float16 hv = (_Float16)(acc[mi][ni][r] + bb);
                    out[bhbase + (size_t)(gm & 2047) * HD + hd] =
                        __builtin_bit_cast(unsigned short, hv);
                }
            } else if (z == 1) {
                const int ks   = hd >> 4;
                const int hi2k = (hd >> 3) & 1;
                const int j    = hd & 7;
#pragma unroll
                for (int r = 0; r < 4; ++r) {
                    const int s = (gmBase + r) & 2047;
                    const int t = s >> 6;
                    const int q = ((s >> 5) & 1) * 4 + ks;
                    const _Float16 hv = (_Float16)(acc[mi][ni][r] + bb);
                    out[bhbase + (((size_t)t * 8 + q) * 64 + hi2k * 32 + (s & 31)) * 8 + j] =
                        __builtin_bit_cast(unsigned short, hv);
                }
            } else {
                const int nb  = hd >> 5;
                const int c31 = hd & 31;
                const int q   = nb * 4 + ksg;
                U64cvt uu;
#pragma unroll
                for (int r = 0; r < 4; ++r)
                    uu.h[r] = (_Float16)(acc[mi][ni][r] + bb);
                *(ushort4*)(out + bhbase +
                    (((size_t)tV * 8 + q) * 64 + hi2v * 32 + c31) * 8 + jb) = uu.u;
            }
        }
    }
}

// ---------------------------------------------------------------------------
// Flash attention fwd (r18 structure, 8-WAVE BLOCKS): 512 threads, QBLK=256
// (32 q-rows/wave, per-wave code identical to r18). The 33KB K/V LDS tile is
// shared by 8 waves instead of 4: occupancy doubles (2 blocks x 8 waves =
// 16 waves/CU, VGPR-limited) and staging per thread halves (1 gld16 each for
// K and V). Fragment-major K/V, double-buffered, ONE barrier per kv-tile.
// Lane-local no-max softmax; in-register P->A-frag; lsum via fdot2.
// ---------------------------------------------------------------------------
__global__ __launch_bounds__(512)
void attn_f16(const unsigned short* __restrict__ qh,
              const unsigned short* __restrict__ kf,
              const unsigned short* __restrict__ vf,
              const float* __restrict__ mask,
              float* __restrict__ out)
{
    // bijective XCD swizzle: 512 blocks, XCD x covers bh in [x*8, x*8+8)
    const int flat = blockIdx.y * gridDim.x + blockIdx.x;   // 0..511
    const int sw   = (flat & 7) * 64 + (flat >> 3);
    const int bh   = sw >> 3;
    const int q0   = (sw & 7) * 256;

    const int b = bh >> 4;
    const int h = bh & 15;
    const unsigned short* Q  = qh + (size_t)bh * S * HD;
    const unsigned short* KF = kf + (size_t)bh * S * HD;   // frag-major
    const unsigned short* VF = vf + (size_t)bh * S * HD;   // frag-major

    const int tid  = threadIdx.x;       // 0..511
    const int lane = tid & 63;
    const int wid  = tid >> 6;          // 0..7
    const int l31  = lane & 31;
    const int hi2  = lane >> 5;

    __shared__ __align__(16) unsigned char Kl[2][8192];   // fragment-major
    __shared__ __align__(16) unsigned char Vl[2][8192];
    __shared__ __align__(16) float maskb[2][64];

    const int ldsW = wid * 1024;     // wave-uniform LDS base (this wave's chunk group)
    const int g0   = tid * 8;        // elem offset of this thread's 16B chunk

    // p = exp2(s * C + maskterm), C = 0.125*log2(e); maskterm folds mask+SHIFT
    const float C = 0.18033688011112042f;          // 0.125 * log2(e)
    const float SHIFT = -5.770780163555854f;       // -4 * log2(e)

    // hoist Q as the B-operand: col = l31, k = hi2*8 + j (+16*ks)
    f16x8 aq[4];
    {
        const unsigned short* qrow = Q + (size_t)(q0 + wid * 32 + l31) * HD;
#pragma unroll
        for (int ks = 0; ks < 4; ++ks)
            aq[ks] = *(const f16x8*)(qrow + ks * 16 + hi2 * 8);
    }

    float ls0 = 0.f, ls1 = 0.f;
    f32x16 accO[2];
    accO[0] = (f32x16){};
    accO[1] = (f32x16){};
    const h16x2 one2 = {(__fp16)1.0f, (__fp16)1.0f};

    // ---- prologue: stage tile 0 into buf 0 (1 chunk per thread per tensor) ----
    gld16(KF + g0, Kl[0] + ldsW);
    gld16(VF + g0, Vl[0] + ldsW);
    if (tid < 64)
        maskb[0][tid] = fmaf(1.0f - mask[(size_t)b * S + tid], -1.4426950408889634e30f, SHIFT);
    __syncthreads();

    const int lane16 = lane * 16;
    for (int t = 0; t < S / 64; ++t) {
        const int cb = t & 1, nx = cb ^ 1;
        const unsigned char* Kc = Kl[cb];
        const unsigned char* Vc = Vl[cb];

        // ---- stage next tile FIRST (buffer nx is dead since prev barrier) ----
        if (t < S / 64 - 1) {
            const int nt = (t + 1) * 4096;   // 4096 elems per (tile, K or V)
            gld16(KF + nt + g0, Kl[nx] + ldsW);
            gld16(VF + nt + g0, Vl[nx] + ldsW);
            if (tid < 64)
                maskb[nx][tid] = fmaf(1.0f - mask[(size_t)b * S + (t + 1) * 64 + tid],
                                      -1.4426950408889634e30f, SHIFT);
        }

        // ---- QK^T (swapped): p[kb] = K x Q, col = q, row = kv ----
        f32x16 p[2];
        p[0] = (f32x16){};
        p[1] = (f32x16){};
        __builtin_amdgcn_s_setprio(1);
#pragma unroll
        for (int kb = 0; kb < 2; ++kb)
#pragma unroll
            for (int ks = 0; ks < 4; ++ks) {
                const f16x8 ak = *(const f16x8*)(Kc + lane16 + (kb * 4 + ks) * 1024);
                p[kb] = __builtin_amdgcn_mfma_f32_32x32x16_f16(ak, aq[ks], p[kb], 0, 0, 0);
            }
        __builtin_amdgcn_s_setprio(0);

        // ---- lane-local softmax + in-register P->A-frag ----
        f16x8 pa[4];
#pragma unroll
        for (int kb = 0; kb < 2; ++kb) {
            float pe[16];
#pragma unroll
            for (int g = 0; g < 4; ++g) {
                const f32x4 mg = *(const f32x4*)(&maskb[cb][kb * 32 + g * 8 + hi2 * 4]);
#pragma unroll
                for (int e = 0; e < 4; ++e)
                    pe[g * 4 + e] = exp2f(fmaf(p[kb][g * 4 + e], C, mg[e]));
            }
#pragma unroll
            for (int ks2 = 0; ks2 < 2; ++ks2) {
                const int o = ks2 * 8;
                const h16x2 h0 = __builtin_amdgcn_cvt_pkrtz(pe[o + 0], pe[o + 1]);
                const h16x2 h1 = __builtin_amdgcn_cvt_pkrtz(pe[o + 2], pe[o + 3]);
                const h16x2 h2 = __builtin_amdgcn_cvt_pkrtz(pe[o + 4], pe[o + 5]);
                const h16x2 h3 = __builtin_amdgcn_cvt_pkrtz(pe[o + 6], pe[o + 7]);
                ls0 = __builtin_amdgcn_fdot2(h0, one2, ls0, false);
                ls1 = __builtin_amdgcn_fdot2(h1, one2, ls1, false);
                ls0 = __builtin_amdgcn_fdot2(h2, one2, ls0, false);
                ls1 = __builtin_amdgcn_fdot2(h3, one2, ls1, false);
                u32 a0 = __builtin_bit_cast(u32, h0);
                u32 a1 = __builtin_bit_cast(u32, h1);
                u32 a2 = __builtin_bit_cast(u32, h2);
                u32 a3 = __builtin_bit_cast(u32, h3);
                asm volatile("v_permlane32_swap_b32 %0, %1" : "+v"(a0), "+v"(a2));
                asm volatile("v_permlane32_swap_b32 %0, %1" : "+v"(a1), "+v"(a3));
                W4 w;
                w.w[0] = a0; w.w[1] = a1; w.w[2] = a2; w.w[3] = a3;
                pa[kb * 2 + ks2] = w.v;
            }
        }

        // ---- PV: accO[nb] += P x V ----
        __builtin_amdgcn_s_setprio(1);
#pragma unroll
        for (int nb = 0; nb < 2; ++nb)
#pragma unroll
            for (int ksg = 0; ksg < 4; ++ksg) {
                const f16x8 bv = *(const f16x8*)(Vc + lane16 + (nb * 4 + ksg) * 1024);
                accO[nb] = __builtin_amdgcn_mfma_f32_32x32x16_f16(pa[ksg], bv, accO[nb], 0, 0, 0);
            }
        __builtin_amdgcn_s_setprio(0);

        __syncthreads();   // drains vmcnt: next buffer ready
    }

    // ---- epilogue: finish lsum (one xor-32), redistribute 1/l, store ----
    float lsum = ls0 + ls1;
    lsum += __shfl_xor(lsum, 32);
    const float linv = 1.0f / lsum;

    float lr[16];
#pragma unroll
    for (int r = 0; r < 16; ++r)
        lr[r] = __shfl(linv, (r & 3) + 8 * (r >> 2) + 4 * hi2);

#pragma unroll
    for (int nb = 0; nb < 2; ++nb) {
        const int dcol = h * HD + nb * 32 + l31;
#pragma unroll
        for (int r = 0; r < 16; ++r) {
            const int qrow = q0 + wid * 32 + (r & 3) + 8 * (r >> 2) + 4 * hi2;
            out[((size_t)b * S + qrow) * D + dcol] = accO[nb][r] * lr[r];
        }
    }
}

// ---------------------------------------------------------------------------
extern "C" void kernel_launch(void* const* d_in, const int* in_sizes, int n_in,
                              void* d_out, int out_size, void* d_ws, size_t ws_size,
                              hipStream_t stream)
{
    const float* q    = (const float*)d_in[0];
    const float* k    = (const float*)d_in[1];
    const float* v    = (const float*)d_in[2];
    const float* mask = (const float*)d_in[3];
    const float* wq   = (const float*)d_in[4];
    const float* bq   = (const float*)d_in[5];
    const float* wk   = (const float*)d_in[6];
    const float* bk   = (const float*)d_in[7];
    const float* wv   = (const float*)d_in[8];
    const float* bv   = (const float*)d_in[9];

    unsigned short* ws = (unsigned short*)d_ws;
    const size_t per  = (size_t)B * S * D;          // 8,388,608
    const size_t wsz  = 1048576;                    // one weight matrix (f16)
    const size_t need = (3 * per + 3 * wsz + 3 * per) * 2;

    dim3 ga(S / 256, B * H);
    if (ws_size >= need) {
        unsigned short* af16 = ws;
        unsigned short* wf16 = ws + 3 * per;
        unsigned short* outs = ws + 3 * per + 3 * wsz;
        cvt_prep<<<13824, 256, 0, stream>>>(q, k, v, wq, wk, wv, af16);
        proj_f16<<<1536, 256, 0, stream>>>(af16, wf16, bq, bk, bv, outs);
        attn_f16<<<ga, 512, 0, stream>>>(outs, outs + per, outs + 2 * per, mask, (float*)d_out);
    } else {
        proj_qkv<<<1536, 256, 0, stream>>>(q, k, v, wq, wk, wv, bq, bk, bv, ws);
        attn_f16<<<ga, 512, 0, stream>>>(ws, ws + per, ws + 2 * per, mask, (float*)d_out);
    }
}